// Round 7
// baseline (189.655 us; speedup 1.0000x reference)
//
#include <hip/hip_runtime.h>

// ---------------------------------------------------------------------------
// DigitConvolutionalModel: x(32768,784) -> conv3x3(valid) -> 676
//   -> relu(@W1(676,300)+b1) -> relu(@W2(300,300)+b2) -> @W3(300,10)+b3
//
// R7: barrier-minimal fused kernel (18 barriers vs R6's ~52).
//  - B-fragments: global -> REGISTERS (L2-hot, coalesced 1KB/load, wave-
//    private, no barriers, no LDS). stage16 machinery deleted.
//  - A (x): R5's sequential-order band staging into LDS (the proven DRAM fix),
//    7 bands x (2 barriers), fp32->bf16.
//  - M=128 rows/block, 256 blocks, 512 thr = 8 waves = 2 mq x 4 nq;
//    wave = 64 rows (4 m-tiles) x 80 cols (5 n-tiles), acc 80 VGPR.
//  - h1/h2: ONE whole-tile exchange each through an 80KB LDS arena
//    (128 x 320 bf16 in A-frag order); GEMM2/GEMM3 K-loops barrier-free.
// ---------------------------------------------------------------------------

typedef __bf16 bf16_t;
typedef __bf16 bf16x4 __attribute__((ext_vector_type(4)));
typedef __bf16 bf16x8 __attribute__((ext_vector_type(8)));
typedef float  f32x4  __attribute__((ext_vector_type(4)));

#define MFMA16(a, b, c) __builtin_amdgcn_mfma_f32_16x16x32_bf16((a), (b), (c), 0, 0, 0)

#define W1F_ELEMS (25 * 20 * 64 * 8)  // 256000  (K=800, N=320)
#define W2F_ELEMS (10 * 20 * 64 * 8)  // 102400  (K=320, N=320)
#define W3F_ELEMS (10 * 1 * 64 * 8)   // 5120    (K=320, N=16)
#define ASTRIDE   136                 // bf16 row stride in Abuf (272B)

// ---------------------------------------------------------------------------
__global__ void prep_weights(const float* __restrict__ conv_w,
                             const float* __restrict__ W1,
                             const float* __restrict__ W2,
                             const float* __restrict__ W3,
                             bf16_t* __restrict__ W1f,
                             bf16_t* __restrict__ W2f,
                             bf16_t* __restrict__ W3f) {
    int idx = blockIdx.x * 256 + threadIdx.x;
    if (idx < 800 * 320) {
        int k = idx / 320;
        int n = idx - k * 320;
        float v = 0.0f;
        if (k < 784 && n < 300) {
            int py = k / 28;
            int px = k - py * 28;
#pragma unroll
            for (int ky = 0; ky < 3; ++ky) {
                int oy = py - ky;
                if (oy < 0 || oy > 25) continue;
#pragma unroll
                for (int kx = 0; kx < 3; ++kx) {
                    int ox = px - kx;
                    if (ox < 0 || ox > 25) continue;
                    v += conv_w[ky * 3 + kx] * W1[(oy * 26 + ox) * 300 + n];
                }
            }
        }
        int kc = k >> 5, quad = (k >> 3) & 3, j = k & 7;
        int nt = n >> 4, nin = n & 15;
        W1f[(((kc * 20 + nt) * 64 + quad * 16 + nin) << 3) + j] = (bf16_t)v;
    } else if (idx < 800 * 320 + 320 * 320) {
        int i2 = idx - 800 * 320;
        int k = i2 / 320;
        int n = i2 - k * 320;
        float v = (k < 300 && n < 300) ? W2[k * 300 + n] : 0.0f;
        int kc = k >> 5, quad = (k >> 3) & 3, j = k & 7;
        int nt = n >> 4, nin = n & 15;
        W2f[(((kc * 20 + nt) * 64 + quad * 16 + nin) << 3) + j] = (bf16_t)v;
    } else if (idx < 800 * 320 + 320 * 320 + 320 * 16) {
        int i3 = idx - (800 * 320 + 320 * 320);
        int k = i3 / 16;
        int n = i3 - k * 16;
        float v = (k < 300 && n < 10) ? W3[k * 10 + n] : 0.0f;
        int kc = k >> 5, quad = (k >> 3) & 3, j = k & 7;
        W3f[(((kc * 64) + quad * 16 + n) << 3) + j] = (bf16_t)v;
    }
}

// ---------------------------------------------------------------------------
// Fused: out = relu(relu(x@W1eff+b1)@W2+b2)@W3+b3.
// A-frag (16x16x32): A[m=lane&15][k=(lane>>4)*8+j]
// C/D: col=lane&15, row=(lane>>4)*4+reg
// ---------------------------------------------------------------------------
__global__ __launch_bounds__(512, 2) void fused_mlp(
    const float* __restrict__ x, const float* __restrict__ b1,
    const float* __restrict__ b2, const float* __restrict__ b3,
    const bf16x8* __restrict__ W1f, const bf16x8* __restrict__ W2f,
    const bf16x8* __restrict__ W3f, float* __restrict__ out) {
    __shared__ bf16x8 arena[5120];  // 80 KB: Abuf (GEMM1) -> h exchange

    const int tid = threadIdx.x;
    const int w   = tid >> 6;
    const int l   = tid & 63;
    const int q   = l >> 4;
    const int l15 = l & 15;
    const int mq  = w >> 2;   // 0..1: rows mq*64..+63
    const int nq  = w & 3;    // 0..3: cols nq*80..+79
    const int r0  = blockIdx.x * 128;

    // sequential-stage maps: bands 0-5 (128 rows x 128 cols fp32):
    //   per i: row = i*16 + (tid>>5), float4-col = tid&31  (512B runs/instr)
    const int srow = tid >> 5;
    const int sc4  = tid & 31;
    // band 6 (cols 768..783 + zero-pad 784..799): row = tid>>2, c4 = tid&3
    const int trow = tid >> 2;
    const int tc4  = tid & 3;

    bf16_t* Abuf = (bf16_t*)arena;  // [128][ASTRIDE] during GEMM1

    // prefetch band 0
    float4 pf[8];
#pragma unroll
    for (int i = 0; i < 8; ++i)
        pf[i] = *(const float4*)(x + (size_t)(r0 + i * 16 + srow) * 784 + sc4 * 4);

    f32x4 acc1[4][5];
#pragma unroll
    for (int mt = 0; mt < 4; ++mt)
#pragma unroll
        for (int nt = 0; nt < 5; ++nt) acc1[mt][nt] = (f32x4){0.f, 0.f, 0.f, 0.f};

    // ---------------- GEMM1: 7 bands, chunks barrier-free ------------------
    for (int band = 0; band < 7; ++band) {
        __syncthreads();  // previous band's Abuf reads complete

        if (band < 6) {
#pragma unroll
            for (int i = 0; i < 8; ++i) {
                bf16x4 v;
                v[0] = (bf16_t)pf[i].x; v[1] = (bf16_t)pf[i].y;
                v[2] = (bf16_t)pf[i].z; v[3] = (bf16_t)pf[i].w;
                *(bf16x4*)&Abuf[(i * 16 + srow) * ASTRIDE + sc4 * 4] = v;
            }
        } else {
            bf16x4 v;
            v[0] = (bf16_t)pf[0].x; v[1] = (bf16_t)pf[0].y;
            v[2] = (bf16_t)pf[0].z; v[3] = (bf16_t)pf[0].w;
            *(bf16x4*)&Abuf[trow * ASTRIDE + tc4 * 4] = v;
            bf16x4 z = (bf16x4){(bf16_t)0.f, (bf16_t)0.f, (bf16_t)0.f, (bf16_t)0.f};
            *(bf16x4*)&Abuf[trow * ASTRIDE + 16 + tc4 * 4] = z;  // cols 784..799
        }
        __syncthreads();  // Abuf visible

        // prefetch next band (drained at next band-top barrier, ~4 chunks later)
        if (band + 1 < 6) {
#pragma unroll
            for (int i = 0; i < 8; ++i)
                pf[i] = *(const float4*)(x + (size_t)(r0 + i * 16 + srow) * 784 +
                                         (band + 1) * 128 + sc4 * 4);
        } else if (band + 1 == 6) {
            pf[0] = *(const float4*)(x + (size_t)(r0 + trow) * 784 + 768 + tc4 * 4);
        }

        const int nch = (band < 6) ? 4 : 1;
        for (int kcl = 0; kcl < nch; ++kcl) {
            const int kc = band * 4 + kcl;
            // B-frags straight from global (L2-hot), wave-private
            bf16x8 bfr[5];
            const bf16x8* wb = W1f + ((size_t)kc * 20 + nq * 5) * 64 + l;
#pragma unroll
            for (int nt = 0; nt < 5; ++nt) bfr[nt] = wb[nt * 64];
#pragma unroll
            for (int mt = 0; mt < 4; ++mt) {
                bf16x8 a = *(const bf16x8*)&Abuf[(mq * 64 + mt * 16 + l15) * ASTRIDE +
                                                 kcl * 32 + q * 8];
#pragma unroll
                for (int nt = 0; nt < 5; ++nt)
                    acc1[mt][nt] = MFMA16(a, bfr[nt], acc1[mt][nt]);
            }
        }
    }
    __syncthreads();  // all Abuf reads done before h1 exchange overwrite

    // ---------------- h1 = relu(C1+b1) -> arena, A-frag order --------------
    // layout: [kc2 (k/32)][mtg (0..7)][64 lanes][8]  == 80 KB
    {
        bf16_t* hb = (bf16_t*)arena;
#pragma unroll
        for (int nt = 0; nt < 5; ++nt) {
            int n = nq * 80 + nt * 16 + l15;
            float bias = (n < 300) ? b1[n] : 0.0f;
            int kc2 = n >> 5, quad = (n >> 3) & 3, j = n & 7;
#pragma unroll
            for (int mt = 0; mt < 4; ++mt) {
                int mtg = mq * 4 + mt;
#pragma unroll
                for (int r = 0; r < 4; ++r) {
                    float v = acc1[mt][nt][r] + bias;
                    v = v > 0.f ? v : 0.f;
                    hb[(((kc2 * 8 + mtg) * 64 + quad * 16 + q * 4 + r) << 3) + j] =
                        (bf16_t)v;
                }
            }
        }
    }
    __syncthreads();

    // ---------------- GEMM2: 10 chunks, barrier-free -----------------------
    f32x4 acc2[4][5];
#pragma unroll
    for (int mt = 0; mt < 4; ++mt)
#pragma unroll
        for (int nt = 0; nt < 5; ++nt) acc2[mt][nt] = (f32x4){0.f, 0.f, 0.f, 0.f};
    for (int kc = 0; kc < 10; ++kc) {
        bf16x8 b2f[5];
        const bf16x8* wb = W2f + ((size_t)kc * 20 + nq * 5) * 64 + l;
#pragma unroll
        for (int nt = 0; nt < 5; ++nt) b2f[nt] = wb[nt * 64];
#pragma unroll
        for (int mt = 0; mt < 4; ++mt) {
            bf16x8 a = arena[(kc * 8 + mq * 4 + mt) * 64 + l];
#pragma unroll
            for (int nt = 0; nt < 5; ++nt)
                acc2[mt][nt] = MFMA16(a, b2f[nt], acc2[mt][nt]);
        }
    }
    __syncthreads();  // GEMM2 done reading h1

    // ---------------- h2 = relu(C2+b2) -> arena ----------------------------
    {
        bf16_t* hb = (bf16_t*)arena;
#pragma unroll
        for (int nt = 0; nt < 5; ++nt) {
            int n = nq * 80 + nt * 16 + l15;
            float bias = (n < 300) ? b2[n] : 0.0f;
            int kc2 = n >> 5, quad = (n >> 3) & 3, j = n & 7;
#pragma unroll
            for (int mt = 0; mt < 4; ++mt) {
                int mtg = mq * 4 + mt;
#pragma unroll
                for (int r = 0; r < 4; ++r) {
                    float v = acc2[mt][nt][r] + bias;
                    v = v > 0.f ? v : 0.f;
                    hb[(((kc2 * 8 + mtg) * 64 + quad * 16 + q * 4 + r) << 3) + j] =
                        (bf16_t)v;
                }
            }
        }
    }
    __syncthreads();

    // ---------------- GEMM3: wave w -> m-tile w (8 tiles, all waves) -------
    f32x4 acc3 = (f32x4){0.f, 0.f, 0.f, 0.f};
#pragma unroll
    for (int kc = 0; kc < 10; ++kc)
        acc3 = MFMA16(arena[(kc * 8 + w) * 64 + l], W3f[kc * 64 + l], acc3);
    if (l15 < 10) {
        float bias = b3[l15];
#pragma unroll
        for (int r = 0; r < 4; ++r)
            out[(size_t)(r0 + w * 16 + q * 4 + r) * 10 + l15] = acc3[r] + bias;
    }
}

// ---------------------------------------------------------------------------
extern "C" void kernel_launch(void* const* d_in, const int* in_sizes, int n_in,
                              void* d_out, int out_size, void* d_ws, size_t ws_size,
                              hipStream_t stream) {
    const float* x      = (const float*)d_in[0];
    const float* conv_w = (const float*)d_in[1];
    const float* W1     = (const float*)d_in[2];
    const float* b1     = (const float*)d_in[3];
    const float* W2     = (const float*)d_in[4];
    const float* b2     = (const float*)d_in[5];
    const float* W3     = (const float*)d_in[6];
    const float* b3     = (const float*)d_in[7];
    float* out = (float*)d_out;

    char* ws = (char*)d_ws;
    bf16_t* W1f = (bf16_t*)(ws);
    bf16_t* W2f = (bf16_t*)(ws + (size_t)W1F_ELEMS * 2);
    bf16_t* W3f = (bf16_t*)(ws + (size_t)(W1F_ELEMS + W2F_ELEMS) * 2);
    if (ws_size < (size_t)(W1F_ELEMS + W2F_ELEMS + W3F_ELEMS) * 2) return;

    int prep_total = 800 * 320 + 320 * 320 + 320 * 16;  // 363520
    prep_weights<<<(prep_total + 255) / 256, 256, 0, stream>>>(
        conv_w, W1, W2, W3, W1f, W2f, W3f);

    fused_mlp<<<32768 / 128, 512, 0, stream>>>(
        x, b1, b2, b3, (const bf16x8*)W1f, (const bf16x8*)W2f,
        (const bf16x8*)W3f, out);
}